// Round 1
// baseline (3809.821 us; speedup 1.0000x reference)
//
#include <hip/hip_runtime.h>

// ---------------------------------------------------------------------------
// GLA_GCN: B=4096, J=25, D_IN=512, D_H=256, D_OUT=512
// Partition analysis: PART_INDICES = {0:[0..4], 1:[5,6,11,12], 2:[5,7,9],
// 3:[6,8,10], 4:[11..16]}. Later .set() overwrites earlier -> partition 1 is
// fully dead. Kept partitions write disjoint joints; 17..24 are zero.
// ---------------------------------------------------------------------------

#define BATCH 4096
#define NJOINT 25
#define DIN 512
#define DH 256
#define DOUT 512
#define MROWS (BATCH * NJOINT)        // 102400
#define SZ_BIG (MROWS * DOUT)         // 52,428,800 floats

// workspace layout (floats)
#define OFF_ADJ 0                      // 0..4095: normalized adjacencies
#define OFF_S   4096                   // big scratch (T, P1, P3, HF reuse)
#define OFF_XL  (OFF_S + SZ_BIG)       // xl buffer (B,25,512)
// total ws need: (4096 + 2*52,428,800) * 4 B ~= 420 MB

// ---------------------------------------------------------------------------
// Adjacency normalization: out[i,j] = d_i * a[i,j] * d_j, d = rsqrt(max(rowsum,1e-6))
// ---------------------------------------------------------------------------
__device__ void norm_one(const float* A, int n, float* out, float* sAdj, float* sD) {
    int t = threadIdx.x;
    for (int i = t; i < n * n; i += 256) sAdj[i] = A[i];
    __syncthreads();
    if (t < n) {
        float s = 0.f;
        for (int j = 0; j < n; j++) s += sAdj[t * n + j];
        sD[t] = 1.0f / sqrtf(fmaxf(s, 1e-6f));
    }
    __syncthreads();
    for (int i = t; i < n * n; i += 256) {
        int r = i / n, c = i % n;
        out[i] = sD[r] * sAdj[i] * sD[c];
    }
    __syncthreads();
}

__global__ __launch_bounds__(256) void adjnorm_kernel(
    const float* Ag, const float* A0, const float* A2, const float* A3,
    const float* A4, float* ADJ) {
    __shared__ float sAdj[640];
    __shared__ float sD[32];
    norm_one(Ag, 25, ADJ, sAdj, sD);                 // global at ADJ[0..624]
    norm_one(A0, 5, ADJ + 640 + 0 * 64, sAdj, sD);   // slot 0: part 0
    norm_one(A2, 3, ADJ + 640 + 1 * 64, sAdj, sD);   // slot 1: part 2
    norm_one(A3, 3, ADJ + 640 + 2 * 64, sAdj, sD);   // slot 2: part 3
    norm_one(A4, 6, ADJ + 640 + 3 * 64, sAdj, sD);   // slot 3: part 4
}

// ---------------------------------------------------------------------------
// zero all of XL (joints 17..24 never written; rest overwritten by scatter)
// ---------------------------------------------------------------------------
__global__ __launch_bounds__(256) void zero_buf(float* p, int n) {
    int id = blockIdx.x * 256 + threadIdx.x;
    if (id < n) p[id] = 0.f;
}

// ---------------------------------------------------------------------------
// Generic fp32 GEMM: C[M,N] = act(A@W + bias)
// 64x64 tile, 256 threads, 4x4 microtile, K step 16. M,N mult of 64; K mult 16.
// GATHER: A row m -> x row (m/gn)*25 + idx[m%gn]   (lda = 512)
// CONCAT: K=1024, first 512 from A, rest from A2 (both lda = 512)
// ---------------------------------------------------------------------------
template <bool GATHER, bool CONCAT, bool BIAS, bool RELU>
__global__ __launch_bounds__(256) void gemm64(
    const float* __restrict__ A, const float* __restrict__ A2,
    const float* __restrict__ W, const float* __restrict__ bias,
    float* __restrict__ C, int M, int N, int K,
    int gn, int g0, int g1, int g2, int g3, int g4, int g5) {
    __shared__ float As[16][64];   // [k][m]
    __shared__ float Bs[16][64];   // [k][n]
    int t = threadIdx.x;
    int tx = t & 15, ty = t >> 4;
    int bm = blockIdx.y * 64, bn = blockIdx.x * 64;

    int arow = bm + (t >> 2);
    int asrc;
    if (GATHER) {
        int b = arow / gn;
        int jj = arow - b * gn;
        int jidx;
        switch (jj) {
            case 0: jidx = g0; break;
            case 1: jidx = g1; break;
            case 2: jidx = g2; break;
            case 3: jidx = g3; break;
            case 4: jidx = g4; break;
            default: jidx = g5; break;
        }
        asrc = b * 25 + jidx;
    } else {
        asrc = arow;
    }
    int ak = (t & 3) * 4;       // k offset for A load
    int bk = t >> 4;            // k row for B load
    int bnl = (t & 15) * 4;     // n offset for B load

    float acc[4][4];
#pragma unroll
    for (int i = 0; i < 4; i++)
#pragma unroll
        for (int j = 0; j < 4; j++) acc[i][j] = 0.f;

    for (int k0 = 0; k0 < K; k0 += 16) {
        const float* ap;
        if (CONCAT) {
            ap = (k0 < 512) ? (A + asrc * 512 + k0 + ak)
                            : (A2 + asrc * 512 + (k0 - 512) + ak);
        } else {
            ap = A + asrc * K + k0 + ak;
        }
        float4 a4 = *(const float4*)ap;
        float4 b4 = *(const float4*)(W + (k0 + bk) * N + bn + bnl);
        __syncthreads();
        As[ak + 0][t >> 2] = a4.x;
        As[ak + 1][t >> 2] = a4.y;
        As[ak + 2][t >> 2] = a4.z;
        As[ak + 3][t >> 2] = a4.w;
        *(float4*)&Bs[bk][bnl] = b4;
        __syncthreads();
#pragma unroll
        for (int kk = 0; kk < 16; kk++) {
            float4 av = *(const float4*)&As[kk][ty * 4];
            float4 bv = *(const float4*)&Bs[kk][tx * 4];
            float am[4] = {av.x, av.y, av.z, av.w};
            float bw[4] = {bv.x, bv.y, bv.z, bv.w};
#pragma unroll
            for (int i = 0; i < 4; i++)
#pragma unroll
                for (int j = 0; j < 4; j++) acc[i][j] += am[i] * bw[j];
        }
    }

#pragma unroll
    for (int i = 0; i < 4; i++) {
        int row = bm + ty * 4 + i;
        float vals[4];
#pragma unroll
        for (int j = 0; j < 4; j++) {
            float v = acc[i][j];
            if (BIAS) v += bias[bn + tx * 4 + j];
            if (RELU) v = fmaxf(v, 0.f);
            vals[j] = v;
        }
        float4 o = {vals[0], vals[1], vals[2], vals[3]};
        *(float4*)(C + row * N + bn + tx * 4) = o;
    }
}

// ---------------------------------------------------------------------------
// In-place joint mix: T (B, NJ, F); T[b,i,f] = relu(sum_j adj[i,j]*T[b,j,f] + bias[f])
// One thread per (b,f); reads all NJ before writing -> in-place safe.
// ---------------------------------------------------------------------------
template <int NJ>
__global__ __launch_bounds__(256) void mix_inplace(
    float* __restrict__ T, const float* __restrict__ adjn,
    const float* __restrict__ bias, int F) {
    __shared__ float As[NJ * NJ];
    int t = threadIdx.x;
    for (int i = t; i < NJ * NJ; i += 256) As[i] = adjn[i];
    __syncthreads();
    int id = blockIdx.x * 256 + t;
    int f = id % F;
    int b = id / F;
    float v[NJ];
    float* base = T + (b * NJ) * F + f;
#pragma unroll
    for (int j = 0; j < NJ; j++) v[j] = base[j * F];
    float bi = bias[f];
#pragma unroll
    for (int i = 0; i < NJ; i++) {
        float o = 0.f;
#pragma unroll
        for (int j = 0; j < NJ; j++) o += As[i * NJ + j] * v[j];
        base[i * F] = fmaxf(o + bi, 0.f);
    }
}

// ---------------------------------------------------------------------------
// Local layer-b mix + scatter into XL at this partition's joints (F=512)
// ---------------------------------------------------------------------------
template <int NJ>
__global__ __launch_bounds__(256) void mix_scatter(
    const float* __restrict__ P, const float* __restrict__ adjn,
    const float* __restrict__ bias, float* __restrict__ XL,
    int j0, int j1, int j2, int j3, int j4, int j5) {
    __shared__ float As[NJ * NJ];
    __shared__ int jm[NJ];
    int t = threadIdx.x;
    for (int i = t; i < NJ * NJ; i += 256) As[i] = adjn[i];
    if (t == 0) {
        int tmp[6] = {j0, j1, j2, j3, j4, j5};
        for (int i = 0; i < NJ; i++) jm[i] = tmp[i];
    }
    __syncthreads();
    int id = blockIdx.x * 256 + t;
    int f = id & 511;
    int b = id >> 9;
    float v[NJ];
    const float* base = P + (b * NJ) * 512 + f;
#pragma unroll
    for (int j = 0; j < NJ; j++) v[j] = base[j * 512];
    float bi = bias[f];
#pragma unroll
    for (int i = 0; i < NJ; i++) {
        float o = 0.f;
#pragma unroll
        for (int j = 0; j < NJ; j++) o += As[i * NJ + j] * v[j];
        XL[(b * 25 + jm[i]) * 512 + f] = fmaxf(o + bi, 0.f);
    }
}

// ---------------------------------------------------------------------------
extern "C" void kernel_launch(void* const* d_in, const int* in_sizes, int n_in,
                              void* d_out, int out_size, void* d_ws,
                              size_t ws_size, hipStream_t stream) {
    const float* x    = (const float*)d_in[0];
    const float* adjg = (const float*)d_in[1];
    const float* al0  = (const float*)d_in[2];
    // d_in[3] = adj_local_1: dead partition, unused
    const float* al2  = (const float*)d_in[4];
    const float* al3  = (const float*)d_in[5];
    const float* al4  = (const float*)d_in[6];
    const float* Wg0  = (const float*)d_in[7];
    const float* bg0  = (const float*)d_in[8];
    const float* Wg1  = (const float*)d_in[9];
    const float* bg1  = (const float*)d_in[10];
    const float* Wf0  = (const float*)d_in[31];
    const float* bf0  = (const float*)d_in[32];
    const float* Wf1  = (const float*)d_in[33];
    const float* bf1  = (const float*)d_in[34];

    float* ws  = (float*)d_ws;
    float* ADJ = ws + OFF_ADJ;
    float* S   = ws + OFF_S;
    float* XL  = ws + OFF_XL;
    float* XG  = (float*)d_out;        // stage xg in d_out; overwritten by f1
    float* T   = S;                    // (B,25,256)
    float* P3  = S;                    // (B,n,512)  locals phase (T dead)
    float* P1  = S + 16777216;         // (B,n,256)
    float* HF  = S;                    // (B,25,512) fusion phase (locals dead)

    dim3 blk(256);

    adjnorm_kernel<<<1, blk, 0, stream>>>(adjg, al0, al2, al3, al4, ADJ);
    zero_buf<<<(SZ_BIG + 255) / 256, blk, 0, stream>>>(XL, SZ_BIG);

    // global branch: T = x@Wg0 ; mix+relu ; XG = T@Wg1 ; mix+relu
    gemm64<false, false, false, false><<<dim3(4, 1600), blk, 0, stream>>>(
        x, nullptr, Wg0, nullptr, T, MROWS, 256, 512, 0, 0, 0, 0, 0, 0, 0);
    mix_inplace<25><<<BATCH * 256 / 256, blk, 0, stream>>>(T, ADJ, bg0, 256);
    gemm64<false, false, false, false><<<dim3(8, 1600), blk, 0, stream>>>(
        T, nullptr, Wg1, nullptr, XG, MROWS, 512, 256, 0, 0, 0, 0, 0, 0, 0);
    mix_inplace<25><<<BATCH * 512 / 256, blk, 0, stream>>>(XG, ADJ, bg1, 512);

    // local branch: partitions 0,2,3,4 (partition 1 dead)
    struct Part { int n, slot, widx; int idx[6]; };
    const Part parts[4] = {
        {5, 0, 11, {0, 1, 2, 3, 4, 0}},
        {3, 1, 19, {5, 7, 9, 0, 0, 0}},
        {3, 2, 23, {6, 8, 10, 0, 0, 0}},
        {6, 3, 27, {11, 12, 13, 14, 15, 16}},
    };
    for (int q = 0; q < 4; q++) {
        const Part& P = parts[q];
        const float* Wa = (const float*)d_in[P.widx + 0];
        const float* ba = (const float*)d_in[P.widx + 1];
        const float* Wb = (const float*)d_in[P.widx + 2];
        const float* bb = (const float*)d_in[P.widx + 3];
        const float* adjl = ADJ + 640 + P.slot * 64;
        int M = BATCH * P.n;
        gemm64<true, false, false, false><<<dim3(4, M / 64), blk, 0, stream>>>(
            x, nullptr, Wa, nullptr, P1, M, 256, 512, P.n, P.idx[0], P.idx[1],
            P.idx[2], P.idx[3], P.idx[4], P.idx[5]);
        if (P.n == 5)
            mix_inplace<5><<<BATCH * 256 / 256, blk, 0, stream>>>(P1, adjl, ba, 256);
        else if (P.n == 3)
            mix_inplace<3><<<BATCH * 256 / 256, blk, 0, stream>>>(P1, adjl, ba, 256);
        else
            mix_inplace<6><<<BATCH * 256 / 256, blk, 0, stream>>>(P1, adjl, ba, 256);
        gemm64<false, false, false, false><<<dim3(8, M / 64), blk, 0, stream>>>(
            P1, nullptr, Wb, nullptr, P3, M, 512, 256, 0, 0, 0, 0, 0, 0, 0);
        if (P.n == 5)
            mix_scatter<5><<<BATCH * 512 / 256, blk, 0, stream>>>(
                P3, adjl, bb, XL, P.idx[0], P.idx[1], P.idx[2], P.idx[3], P.idx[4], P.idx[5]);
        else if (P.n == 3)
            mix_scatter<3><<<BATCH * 512 / 256, blk, 0, stream>>>(
                P3, adjl, bb, XL, P.idx[0], P.idx[1], P.idx[2], P.idx[3], P.idx[4], P.idx[5]);
        else
            mix_scatter<6><<<BATCH * 512 / 256, blk, 0, stream>>>(
                P3, adjl, bb, XL, P.idx[0], P.idx[1], P.idx[2], P.idx[3], P.idx[4], P.idx[5]);
    }

    // fusion: HF = relu([XG|XL]@Wf0 + bf0) ; out = HF@Wf1 + bf1
    gemm64<false, true, true, true><<<dim3(8, 1600), blk, 0, stream>>>(
        XG, XL, Wf0, bf0, HF, MROWS, 512, 1024, 0, 0, 0, 0, 0, 0, 0);
    gemm64<false, false, true, false><<<dim3(8, 1600), blk, 0, stream>>>(
        HF, nullptr, Wf1, bf1, (float*)d_out, MROWS, 512, 512, 0, 0, 0, 0, 0, 0, 0);

    (void)in_sizes; (void)n_in; (void)out_size; (void)ws_size;
}

// Round 2
// 1116.473 us; speedup vs baseline: 3.4124x; 3.4124x over previous
//
#include <hip/hip_runtime.h>

// ---------------------------------------------------------------------------
// GLA_GCN bf16-MFMA pipeline. B=4096, J=25, D_IN=512, D_H=256, D_OUT=512.
// Partition 1 is dead (all its joints overwritten by parts 2/3/4).
// All GEMMs: 128x128 tile, BK=32, 4 waves x (4x4 of 16x16x32 bf16 MFMA),
// global_load_lds 16B staging, weights pre-transposed to [N][K] bf16.
// ---------------------------------------------------------------------------

#define BATCH 4096
#define NJOINT 25
#define MROWS (BATCH * NJOINT)          // 102400
#define SZ_FULL (MROWS * 512)           // 52,428,800 elements (B,25,512)

typedef __attribute__((ext_vector_type(8))) short short8;
typedef __attribute__((ext_vector_type(4))) float float4_;

__device__ __forceinline__ float b2f(ushort u) {
    union { float f; uint32_t i; } x; x.i = ((uint32_t)u) << 16; return x.f;
}
__device__ __forceinline__ ushort f2b(float f) {
    union { float f; uint32_t i; } x; x.f = f;
    uint32_t r = x.i + 0x7fff + ((x.i >> 16) & 1);
    return (ushort)(r >> 16);
}
__device__ __forceinline__ void async16(const void* g, void* l) {
    __builtin_amdgcn_global_load_lds(
        (const __attribute__((address_space(1))) void*)g,
        (__attribute__((address_space(3))) void*)l, 16, 0, 0);
}

// ---------------------------------------------------------------------------
// Adjacency normalization (fp32, tiny)
// ---------------------------------------------------------------------------
__device__ void norm_one(const float* A, int n, float* out, float* sAdj, float* sD) {
    int t = threadIdx.x;
    for (int i = t; i < n * n; i += 256) sAdj[i] = A[i];
    __syncthreads();
    if (t < n) {
        float s = 0.f;
        for (int j = 0; j < n; j++) s += sAdj[t * n + j];
        sD[t] = 1.0f / sqrtf(fmaxf(s, 1e-6f));
    }
    __syncthreads();
    for (int i = t; i < n * n; i += 256) {
        int r = i / n, c = i % n;
        out[i] = sD[r] * sAdj[i] * sD[c];
    }
    __syncthreads();
}

__global__ __launch_bounds__(256) void adjnorm_kernel(
    const float* Ag, const float* A0, const float* A2, const float* A3,
    const float* A4, float* ADJ) {
    __shared__ float sAdj[640];
    __shared__ float sD[32];
    norm_one(Ag, 25, ADJ, sAdj, sD);
    norm_one(A0, 5, ADJ + 640 + 0 * 64, sAdj, sD);
    norm_one(A2, 3, ADJ + 640 + 1 * 64, sAdj, sD);
    norm_one(A3, 3, ADJ + 640 + 2 * 64, sAdj, sD);
    norm_one(A4, 6, ADJ + 640 + 3 * 64, sAdj, sD);
}

// ---------------------------------------------------------------------------
// fp32 -> bf16 convert (x), float4 -> ushort4
// ---------------------------------------------------------------------------
__global__ __launch_bounds__(256) void cvt_bf16(const float* __restrict__ in,
                                                ushort* __restrict__ out, int n4) {
    int id = blockIdx.x * 256 + threadIdx.x;
    if (id < n4) {
        float4 v = ((const float4*)in)[id];
        ushort4 o;
        o.x = f2b(v.x); o.y = f2b(v.y); o.z = f2b(v.z); o.w = f2b(v.w);
        ((ushort4*)out)[id] = o;
    }
}

// ---------------------------------------------------------------------------
// Weight transpose + convert: W fp32 [K][N] -> Wt bf16 [N][K]. K,N mult of 32.
// ---------------------------------------------------------------------------
__global__ __launch_bounds__(256) void wtrans(const float* __restrict__ W,
                                              ushort* __restrict__ Wt, int K, int N) {
    __shared__ float tile[32][33];
    int t = threadIdx.x;
    int tx = t & 31, ty = t >> 5;  // ty 0..7
    int k0 = blockIdx.y * 32, n0 = blockIdx.x * 32;
    for (int r = ty; r < 32; r += 8)
        tile[r][tx] = W[(size_t)(k0 + r) * N + n0 + tx];
    __syncthreads();
    for (int r = ty; r < 32; r += 8)
        Wt[(size_t)(n0 + r) * K + k0 + tx] = f2b(tile[tx][r]);
}

// ---------------------------------------------------------------------------
// Zero XL joints 17..24 (never written by scatter). 4096*8*512 ushorts.
// ---------------------------------------------------------------------------
__global__ __launch_bounds__(256) void zero_tail(ushort* __restrict__ XL) {
    int id = blockIdx.x * 256 + threadIdx.x;   // 4,194,304 ushort4 writes
    int f4 = id & 127;
    int rj = (id >> 7) & 7;
    int b = id >> 10;
    ushort4 z; z.x = 0; z.y = 0; z.z = 0; z.w = 0;
    ((ushort4*)(XL + ((size_t)(b * 25 + 17 + rj) * 512)))[f4] = z;
}

// ---------------------------------------------------------------------------
// bf16 MFMA GEMM: C[M,N] = act(A @ Wt^T + bias)
//   A: bf16 row-major, leading dim lda (=K except concat)
//   Wt: bf16 [N][K] (pre-transposed)
//   128x128 tile, BK=32, 4 waves, each 64x64 via 4x4 mfma_f32_16x16x32_bf16
//   GATHER: A row m -> Xb row (m/gn)*25 + idx[m%gn]
//   CONCAT: K=1024; k<512 from A, else A2 (both lda 512)
// ---------------------------------------------------------------------------
template <bool GATHER, bool CONCAT, bool BIAS, bool RELU, bool OUTF32>
__global__ __launch_bounds__(256) void mfma_gemm(
    const ushort* __restrict__ A, const ushort* __restrict__ A2,
    const ushort* __restrict__ Wt, const float* __restrict__ bias,
    void* __restrict__ C, int M, int N, int K, int lda,
    int gn, int g0, int g1, int g2, int g3, int g4, int g5) {
    __shared__ ushort As[128][32];
    __shared__ ushort Bs[128][32];
    int t = threadIdx.x;
    int w = t >> 6;       // wave 0..3
    int l = t & 63;       // lane
    int bm = blockIdx.y * 128, bn = blockIdx.x * 128;

    // staging roles: lane l covers row (l>>2), 16B chunk (l&3); wave w rows w*16..+16
    int sr0 = bm + (w << 4) + (l >> 2);
    int sr1 = sr0 + 64;
    int wr0 = bn + (w << 4) + (l >> 2);
    int wr1 = wr0 + 64;
    if (GATHER) {
        int b0 = sr0 / gn, j0 = sr0 - b0 * gn;
        int b1 = sr1 / gn, j1 = sr1 - b1 * gn;
        int map[6] = {g0, g1, g2, g3, g4, g5};
        sr0 = b0 * 25 + map[j0];
        sr1 = b1 * 25 + map[j1];
    }
    int ch = (l & 3) * 8;  // element offset of this lane's 16B chunk

    float4_ acc[4][4];
#pragma unroll
    for (int i = 0; i < 4; i++)
#pragma unroll
        for (int j = 0; j < 4; j++) acc[i][j] = (float4_)0.f;

    int wm = w >> 1, wn = w & 1;
    int lr = l & 15;
    int qk = (l >> 4) * 8;

    for (int k0 = 0; k0 < K; k0 += 32) {
        const ushort *a0, *a1;
        if (CONCAT) {
            const ushort* src = (k0 < 512) ? A : A2;
            int ko = k0 & 511;
            a0 = src + (size_t)sr0 * 512 + ko + ch;
            a1 = src + (size_t)sr1 * 512 + ko + ch;
        } else {
            a0 = A + (size_t)sr0 * lda + k0 + ch;
            a1 = A + (size_t)sr1 * lda + k0 + ch;
        }
        const ushort* b0 = Wt + (size_t)wr0 * K + k0 + ch;
        const ushort* b1 = Wt + (size_t)wr1 * K + k0 + ch;
        async16(a0, &As[(w << 4)][0]);
        async16(a1, &As[64 + (w << 4)][0]);
        async16(b0, &Bs[(w << 4)][0]);
        async16(b1, &Bs[64 + (w << 4)][0]);
        __syncthreads();

        short8 af[4], bf[4];
#pragma unroll
        for (int i = 0; i < 4; i++)
            af[i] = *(const short8*)&As[(wm << 6) + i * 16 + lr][qk];
#pragma unroll
        for (int j = 0; j < 4; j++)
            bf[j] = *(const short8*)&Bs[(wn << 6) + j * 16 + lr][qk];
#pragma unroll
        for (int i = 0; i < 4; i++)
#pragma unroll
            for (int j = 0; j < 4; j++)
                acc[i][j] = __builtin_amdgcn_mfma_f32_16x16x32_bf16(
                    af[i], bf[j], acc[i][j], 0, 0, 0);
        __syncthreads();
    }

    // epilogue: C/D layout col=lane&15, row=(lane>>4)*4+reg
    int quad = l >> 4, cl = l & 15;
#pragma unroll
    for (int j = 0; j < 4; j++) {
        int col = bn + (wn << 6) + j * 16 + cl;
        float bv = BIAS ? bias[col] : 0.f;
#pragma unroll
        for (int i = 0; i < 4; i++) {
#pragma unroll
            for (int r = 0; r < 4; r++) {
                int row = bm + (wm << 6) + i * 16 + (quad << 2) + r;
                float v = acc[i][j][r] + bv;
                if (RELU) v = fmaxf(v, 0.f);
                if (OUTF32)
                    ((float*)C)[(size_t)row * N + col] = v;
                else
                    ((ushort*)C)[(size_t)row * N + col] = f2b(v);
            }
        }
    }
}

// ---------------------------------------------------------------------------
// In-place joint mix on bf16 tensor: T[b,i,f] = relu(sum_j adj[i,j]*T[b,j,f]+bias[f])
// ---------------------------------------------------------------------------
template <int NJ>
__global__ __launch_bounds__(256) void mix_inplace(
    ushort* __restrict__ T, const float* __restrict__ adjn,
    const float* __restrict__ bias, int F) {
    __shared__ float As[NJ * NJ];
    int t = threadIdx.x;
    for (int i = t; i < NJ * NJ; i += 256) As[i] = adjn[i];
    __syncthreads();
    int id = blockIdx.x * 256 + t;
    int f = id % F;
    int b = id / F;
    ushort* base = T + (size_t)(b * NJ) * F + f;
    float v[NJ];
#pragma unroll
    for (int j = 0; j < NJ; j++) v[j] = b2f(base[(size_t)j * F]);
    float bi = bias[f];
#pragma unroll
    for (int i = 0; i < NJ; i++) {
        float o = 0.f;
#pragma unroll
        for (int j = 0; j < NJ; j++) o += As[i * NJ + j] * v[j];
        base[(size_t)i * F] = f2b(fmaxf(o + bi, 0.f));
    }
}

// ---------------------------------------------------------------------------
// Local layer-b mix + scatter into XL (F=512), bf16
// ---------------------------------------------------------------------------
template <int NJ>
__global__ __launch_bounds__(256) void mix_scatter(
    const ushort* __restrict__ P, const float* __restrict__ adjn,
    const float* __restrict__ bias, ushort* __restrict__ XL,
    int j0, int j1, int j2, int j3, int j4, int j5) {
    __shared__ float As[NJ * NJ];
    __shared__ int jm[NJ];
    int t = threadIdx.x;
    for (int i = t; i < NJ * NJ; i += 256) As[i] = adjn[i];
    if (t == 0) {
        int tmp[6] = {j0, j1, j2, j3, j4, j5};
        for (int i = 0; i < NJ; i++) jm[i] = tmp[i];
    }
    __syncthreads();
    int id = blockIdx.x * 256 + t;
    int f = id & 511;
    int b = id >> 9;
    float v[NJ];
    const ushort* base = P + (size_t)(b * NJ) * 512 + f;
#pragma unroll
    for (int j = 0; j < NJ; j++) v[j] = b2f(base[(size_t)j * 512]);
    float bi = bias[f];
#pragma unroll
    for (int i = 0; i < NJ; i++) {
        float o = 0.f;
#pragma unroll
        for (int j = 0; j < NJ; j++) o += As[i * NJ + j] * v[j];
        XL[((size_t)(b * 25 + jm[i])) * 512 + f] = f2b(fmaxf(o + bi, 0.f));
    }
}

// ---------------------------------------------------------------------------
extern "C" void kernel_launch(void* const* d_in, const int* in_sizes, int n_in,
                              void* d_out, int out_size, void* d_ws,
                              size_t ws_size, hipStream_t stream) {
    const float* x    = (const float*)d_in[0];
    const float* adjg = (const float*)d_in[1];
    const float* al0  = (const float*)d_in[2];
    const float* al2  = (const float*)d_in[4];
    const float* al3  = (const float*)d_in[5];
    const float* al4  = (const float*)d_in[6];
    const float* Wg0  = (const float*)d_in[7];
    const float* bg0  = (const float*)d_in[8];
    const float* Wg1  = (const float*)d_in[9];
    const float* bg1  = (const float*)d_in[10];
    const float* Wf0  = (const float*)d_in[31];
    const float* bf0  = (const float*)d_in[32];
    const float* Wf1  = (const float*)d_in[33];
    const float* bf1  = (const float*)d_in[34];

    float* ws = (float*)d_ws;
    float* ADJ = ws;                          // 4096 floats
    ushort* U  = (ushort*)(ws + 4096);
    ushort* Xb = U;                           // (B*25,512) bf16 ; HF reuses this
    ushort* XG = U + (size_t)SZ_FULL;
    ushort* XL = U + (size_t)2 * SZ_FULL;
    ushort* S  = U + (size_t)3 * SZ_FULL;     // 26.2M ushorts
    ushort* T  = S;                           // (B*25,256)
    ushort* P1 = S;                           // (B*n,256) <= 6.3M
    ushort* P3 = S + 6291456;                 // (B*n,512) <= 12.6M
    ushort* Wb = S + 26214400;                // 2.1M ushorts of weights
    ushort* HF = Xb;                          // fusion hidden, reuses Xb

    ushort* Wg0t = Wb;                        // [256][512]
    ushort* Wg1t = Wb + 131072;               // [512][256]
    ushort* Wf0t = Wb + 1310720;              // [512][1024]
    ushort* Wf1t = Wb + 1835008;              // [512][512]

    dim3 blk(256);

    adjnorm_kernel<<<1, blk, 0, stream>>>(adjg, al0, al2, al3, al4, ADJ);
    cvt_bf16<<<SZ_FULL / 4 / 256, blk, 0, stream>>>(x, Xb, SZ_FULL / 4);
    zero_tail<<<16384, blk, 0, stream>>>(XL);

    wtrans<<<dim3(256 / 32, 512 / 32), blk, 0, stream>>>(Wg0, Wg0t, 512, 256);
    wtrans<<<dim3(512 / 32, 256 / 32), blk, 0, stream>>>(Wg1, Wg1t, 256, 512);
    wtrans<<<dim3(512 / 32, 1024 / 32), blk, 0, stream>>>(Wf0, Wf0t, 1024, 512);
    wtrans<<<dim3(512 / 32, 512 / 32), blk, 0, stream>>>(Wf1, Wf1t, 512, 512);

    struct Part { int n, widx; int idx[6]; };
    const Part parts[4] = {
        {5, 11, {0, 1, 2, 3, 4, 0}},
        {3, 19, {5, 7, 9, 0, 0, 0}},
        {3, 23, {6, 8, 10, 0, 0, 0}},
        {6, 27, {11, 12, 13, 14, 15, 16}},
    };
    for (int q = 0; q < 4; q++) {
        ushort* Wat = Wb + 262144 + q * 262144;
        ushort* Wbt = Wat + 131072;
        wtrans<<<dim3(8, 16), blk, 0, stream>>>((const float*)d_in[parts[q].widx], Wat, 512, 256);
        wtrans<<<dim3(16, 8), blk, 0, stream>>>((const float*)d_in[parts[q].widx + 2], Wbt, 256, 512);
    }

    // global branch
    mfma_gemm<false, false, false, false, false><<<dim3(2, 800), blk, 0, stream>>>(
        Xb, nullptr, Wg0t, nullptr, T, MROWS, 256, 512, 512, 0, 0, 0, 0, 0, 0, 0);
    mix_inplace<25><<<BATCH * 256 / 256, blk, 0, stream>>>(T, ADJ, bg0, 256);
    mfma_gemm<false, false, false, false, false><<<dim3(4, 800), blk, 0, stream>>>(
        T, nullptr, Wg1t, nullptr, XG, MROWS, 512, 256, 256, 0, 0, 0, 0, 0, 0, 0);
    mix_inplace<25><<<BATCH * 512 / 256, blk, 0, stream>>>(XG, ADJ, bg1, 512);

    // local branch (parts 0,2,3,4)
    const int slots[4] = {0, 1, 2, 3};
    for (int q = 0; q < 4; q++) {
        const Part& P = parts[q];
        const float* ba = (const float*)d_in[P.widx + 1];
        const float* bb = (const float*)d_in[P.widx + 3];
        ushort* Wat = Wb + 262144 + q * 262144;
        ushort* Wbt = Wat + 131072;
        const float* adjl = ADJ + 640 + slots[q] * 64;
        int M = BATCH * P.n;
        mfma_gemm<true, false, false, false, false><<<dim3(2, M / 128), blk, 0, stream>>>(
            Xb, nullptr, Wat, nullptr, P1, M, 256, 512, 512,
            P.n, P.idx[0], P.idx[1], P.idx[2], P.idx[3], P.idx[4], P.idx[5]);
        if (P.n == 5)
            mix_inplace<5><<<BATCH * 256 / 256, blk, 0, stream>>>(P1, adjl, ba, 256);
        else if (P.n == 3)
            mix_inplace<3><<<BATCH * 256 / 256, blk, 0, stream>>>(P1, adjl, ba, 256);
        else
            mix_inplace<6><<<BATCH * 256 / 256, blk, 0, stream>>>(P1, adjl, ba, 256);
        mfma_gemm<false, false, false, false, false><<<dim3(4, M / 128), blk, 0, stream>>>(
            P1, nullptr, Wbt, nullptr, P3, M, 512, 256, 256, 0, 0, 0, 0, 0, 0, 0);
        if (P.n == 5)
            mix_scatter<5><<<BATCH * 512 / 256, blk, 0, stream>>>(
                P3, adjl, bb, XL, P.idx[0], P.idx[1], P.idx[2], P.idx[3], P.idx[4], P.idx[5]);
        else if (P.n == 3)
            mix_scatter<3><<<BATCH * 512 / 256, blk, 0, stream>>>(
                P3, adjl, bb, XL, P.idx[0], P.idx[1], P.idx[2], P.idx[3], P.idx[4], P.idx[5]);
        else
            mix_scatter<6><<<BATCH * 512 / 256, blk, 0, stream>>>(
                P3, adjl, bb, XL, P.idx[0], P.idx[1], P.idx[2], P.idx[3], P.idx[4], P.idx[5]);
    }

    // fusion: HF = relu([XG|XL]@Wf0 + bf0) ; out = HF@Wf1 + bf1 (fp32 out)
    mfma_gemm<false, true, true, true, false><<<dim3(4, 800), blk, 0, stream>>>(
        XG, XL, Wf0t, bf0, HF, MROWS, 512, 1024, 1024, 0, 0, 0, 0, 0, 0, 0);
    mfma_gemm<false, false, true, false, true><<<dim3(4, 800), blk, 0, stream>>>(
        HF, nullptr, Wf1t, bf1, (float*)d_out, MROWS, 512, 512, 512, 0, 0, 0, 0, 0, 0, 0);

    (void)in_sizes; (void)n_in; (void)out_size; (void)ws_size;
}